// Round 3
// baseline (761.459 us; speedup 1.0000x reference)
//
#include <hip/hip_runtime.h>

#define FIN 512
#define FMID 16
#define FOUT 64

// ============================ CSR build ============================

// Count in-degree AND record each edge's rank among same-dst edges.
// rank[e] = position of edge e within dst[e]'s CSR segment (any order ok).
// 4 edges per thread for ILP (4 independent atomic chains in flight).
__global__ void k_count(const int* __restrict__ dst, int* __restrict__ cnt,
                        int* __restrict__ rank, int E) {
  int t = blockIdx.x * blockDim.x + threadIdx.x;
  int e = t * 4;
  if (e + 3 < E) {
    int4 d = *(const int4*)(dst + e);
    int r0 = atomicAdd(&cnt[d.x], 1);
    int r1 = atomicAdd(&cnt[d.y], 1);
    int r2 = atomicAdd(&cnt[d.z], 1);
    int r3 = atomicAdd(&cnt[d.w], 1);
    *(int4*)(rank + e) = make_int4(r0, r1, r2, r3);
  } else {
    for (; e < E; ++e) rank[e] = atomicAdd(&cnt[dst[e]], 1);
  }
}

// per-256-chunk sums for the hierarchical exclusive scan
__global__ __launch_bounds__(256) void k_blocksum(const int* __restrict__ cnt,
                                                  int* __restrict__ bsum, int n) {
  __shared__ int sm[4];
  int i = blockIdx.x * 256 + threadIdx.x;
  int v = (i < n) ? cnt[i] : 0;
#pragma unroll
  for (int off = 32; off >= 1; off >>= 1) v += __shfl_xor(v, off);
  if ((threadIdx.x & 63) == 0) sm[threadIdx.x >> 6] = v;
  __syncthreads();
  if (threadIdx.x == 0) bsum[blockIdx.x] = sm[0] + sm[1] + sm[2] + sm[3];
}

// single-block exclusive scan of the (<=512) chunk sums
__global__ __launch_bounds__(512) void k_scanb(int* __restrict__ bsum, int nb) {
  __shared__ int sm[512];
  int t = threadIdx.x;
  int v = (t < nb) ? bsum[t] : 0;
  sm[t] = v;
  __syncthreads();
  for (int off = 1; off < 512; off <<= 1) {
    int add = (t >= off) ? sm[t - off] : 0;
    __syncthreads();
    sm[t] += add;
    __syncthreads();
  }
  if (t < nb) bsum[t] = sm[t] - v;  // exclusive
}

// per-chunk exclusive scan + chunk offset -> rowstart[N+1]; also dis = rsqrt(deg+1)
__global__ __launch_bounds__(256) void k_scanf(const int* __restrict__ cnt,
                                               const int* __restrict__ bsum,
                                               int* __restrict__ rowstart,
                                               float* __restrict__ dis, int n) {
  __shared__ int sm[256];
  int t = threadIdx.x;
  int i = blockIdx.x * 256 + t;
  int v = (i < n) ? cnt[i] : 0;
  sm[t] = v;
  __syncthreads();
  for (int off = 1; off < 256; off <<= 1) {
    int add = (t >= off) ? sm[t - off] : 0;
    __syncthreads();
    sm[t] += add;
    __syncthreads();
  }
  int excl = sm[t] - v + bsum[blockIdx.x];
  if (i < n) {
    rowstart[i] = excl;
    dis[i] = rsqrtf((float)v + 1.0f);  // +1 self-loop
  }
  if (i == n - 1) rowstart[n] = excl + v;  // total = E
}

// Atomic-free scatter: position is rowstart[dst] + rank. Pure stores, no RMW.
__global__ void k_scatter(const int* __restrict__ src, const int* __restrict__ dst,
                          const int* __restrict__ rank, const int* __restrict__ rowstart,
                          int* __restrict__ csr_src, int E) {
  int t = blockIdx.x * blockDim.x + threadIdx.x;
  int e = t * 4;
  if (e + 3 < E) {
    int4 s = *(const int4*)(src + e);
    int4 d = *(const int4*)(dst + e);
    int4 r = *(const int4*)(rank + e);
    csr_src[rowstart[d.x] + r.x] = s.x;
    csr_src[rowstart[d.y] + r.y] = s.y;
    csr_src[rowstart[d.z] + r.z] = s.z;
    csr_src[rowstart[d.w] + r.w] = s.w;
  } else {
    for (; e < E; ++e) csr_src[rowstart[dst[e]] + rank[e]] = src[e];
  }
}

// ============================ dense layers ============================

// hs[node, 0:16] = (x[node, 0:512] @ W1) * dis[node].
// One wave per 4-node group: lane = q*16+j; quarter q covers k in
// [q*128, q*128+128), lane j accumulates output j for all 4 nodes.
// W1 transposed into LDS wt[16][512] with XOR swizzle (k ^= (j&7)<<2) so the
// per-step ds_read_b128 spreads 64 lanes over all 32 banks (8 granule-columns
// x 8 rows = the 1KB/128B floor). Each b128 w-read feeds 16 FMAs (4 nodes x 4k),
// cutting LDS wave-instructions 16x vs the b32-per-k version (which measured
// 2.56e7 bank-conflict cycles and 196us = LDS-throughput-bound).
// Grid-stride so the 32KB staging is amortized over many groups.
__global__ __launch_bounds__(256) void k_gemm1(const float* __restrict__ x,
                                               const float* __restrict__ W1,
                                               const float* __restrict__ dis,
                                               float* __restrict__ hs, int n,
                                               int ngroups) {
  __shared__ float wt[FMID * FIN];  // 32 KB, transposed + swizzled
  for (int idx = threadIdx.x; idx < FIN * FMID; idx += 256) {
    int j = idx >> 9, k = idx & 511;
    wt[(j << 9) | (k ^ ((j & 7) << 2))] = W1[k * FMID + j];
  }
  __syncthreads();
  const int lane = threadIdx.x & 63;
  const int q = lane >> 4, j = lane & 15;
  const int jsw = (j & 7) << 2;
  const float* wrow = wt + (j << 9);
  const int gstride = gridDim.x * 4;  // 4 waves per block
  for (int g = blockIdx.x * 4 + (threadIdx.x >> 6); g < ngroups; g += gstride) {
    const int node0 = g * 4;
    const int i1 = min(node0 + 1, n - 1);
    const int i2 = min(node0 + 2, n - 1);
    const int i3 = min(node0 + 3, n - 1);
    const float* r0 = x + (size_t)node0 * FIN + q * 128;
    const float* r1 = x + (size_t)i1 * FIN + q * 128;
    const float* r2 = x + (size_t)i2 * FIN + q * 128;
    const float* r3 = x + (size_t)i3 * FIN + q * 128;
    float a0 = 0.f, a1 = 0.f, a2 = 0.f, a3 = 0.f;
#pragma unroll 8
    for (int t4 = 0; t4 < 32; ++t4) {
      float4 w4 = *(const float4*)(wrow + ((q * 128 + t4 * 4) ^ jsw));
      float4 v0 = *(const float4*)(r0 + t4 * 4);
      float4 v1 = *(const float4*)(r1 + t4 * 4);
      float4 v2 = *(const float4*)(r2 + t4 * 4);
      float4 v3 = *(const float4*)(r3 + t4 * 4);
      a0 += v0.x * w4.x + v0.y * w4.y + v0.z * w4.z + v0.w * w4.w;
      a1 += v1.x * w4.x + v1.y * w4.y + v1.z * w4.z + v1.w * w4.w;
      a2 += v2.x * w4.x + v2.y * w4.y + v2.z * w4.z + v2.w * w4.w;
      a3 += v3.x * w4.x + v3.y * w4.y + v3.z * w4.z + v3.w * w4.w;
    }
    a0 += __shfl_xor(a0, 16); a0 += __shfl_xor(a0, 32);
    a1 += __shfl_xor(a1, 16); a1 += __shfl_xor(a1, 32);
    a2 += __shfl_xor(a2, 16); a2 += __shfl_xor(a2, 32);
    a3 += __shfl_xor(a3, 16); a3 += __shfl_xor(a3, 32);
    if (lane < FMID) {
      hs[(size_t)node0 * FMID + j] = a0 * dis[node0];
      if (node0 + 1 < n) hs[(size_t)(node0 + 1) * FMID + j] = a1 * dis[node0 + 1];
      if (node0 + 2 < n) hs[(size_t)(node0 + 2) * FMID + j] = a2 * dis[node0 + 2];
      if (node0 + 3 < n) hs[(size_t)(node0 + 3) * FMID + j] = a3 * dis[node0 + 3];
    }
  }
}

// CSR gather propagation, float4 rows. 16 lanes per node, split into 4
// subgroups of 4 lanes; subgroup g handles edge slot g, lane-in-subgroup c
// owns features [4c, 4c+4). Per 16-edge batch: one coalesced index load,
// then 16 float4 row-gathers (4 per lane). End: reduce across subgroups.
// Input hs is pre-scaled by dis[src]:
//   raw[d][j] = dis[d] * (hs[d][j] + sum_{s in N(d)} hs[s][j])
// RELU=true (layer 1): out = relu(raw + bias) * dis[d]   (pre-scaled for layer 2)
// RELU=false (layer 2): out = raw                        (k_out adds b2)
template <bool RELU>
__global__ __launch_bounds__(256) void k_prop_csr(const float* __restrict__ hs,
                                                  const int* __restrict__ rowstart,
                                                  const int* __restrict__ csr,
                                                  const float* __restrict__ dis,
                                                  const float* __restrict__ bias,
                                                  float* __restrict__ outp, int n) {
  int t = blockIdx.x * blockDim.x + threadIdx.x;
  int node = t >> 4;
  if (node >= n) return;
  const int j = t & 15;   // lane within 16-group
  const int g = j >> 2;   // subgroup (edge slot)
  const int c = j & 3;    // float4 column
  int beg = rowstart[node], end = rowstart[node + 1];
  float4 acc = make_float4(0.f, 0.f, 0.f, 0.f);
  if (g == 0) {  // self-loop term (already dis[src]-scaled)
    float4 v = ((const float4*)(hs + (size_t)node * FMID))[c];
    acc.x += v.x; acc.y += v.y; acc.z += v.z; acc.w += v.w;
  }
  int i = beg;
  int stop = beg + ((end - beg) & ~15);
  for (; i < stop; i += 16) {
    int sv = csr[i + j];
#pragma unroll
    for (int k = 0; k < 4; ++k) {
      int sidx = __shfl(sv, k * 4 + g, 16);
      float4 v = ((const float4*)(hs + (size_t)sidx * FMID))[c];
      acc.x += v.x; acc.y += v.y; acc.z += v.z; acc.w += v.w;
    }
  }
  // remainder: one edge per step, round-robin over subgroups
  for (int u = 0; i < end; ++i, ++u) {
    int sidx = csr[i];  // uniform within group -> broadcast
    if (g == (u & 3)) {
      float4 v = ((const float4*)(hs + (size_t)sidx * FMID))[c];
      acc.x += v.x; acc.y += v.y; acc.z += v.z; acc.w += v.w;
    }
  }
  // reduce across subgroups (lanes differing in bits 2..3)
#pragma unroll
  for (int off = 4; off <= 8; off <<= 1) {
    acc.x += __shfl_xor(acc.x, off, 16);
    acc.y += __shfl_xor(acc.y, off, 16);
    acc.z += __shfl_xor(acc.z, off, 16);
    acc.w += __shfl_xor(acc.w, off, 16);
  }
  if (g == 0) {
    float dd = dis[node];
    float4 r;
    r.x = dd * acc.x; r.y = dd * acc.y; r.z = dd * acc.z; r.w = dd * acc.w;
    if (RELU) {
      float4 bb = ((const float4*)bias)[c];
      r.x = fmaxf(r.x + bb.x, 0.f) * dd;
      r.y = fmaxf(r.y + bb.y, 0.f) * dd;
      r.z = fmaxf(r.z + bb.z, 0.f) * dd;
      r.w = fmaxf(r.w + bb.w, 0.f) * dd;
    }
    ((float4*)(outp + (size_t)node * FMID))[c] = r;
  }
}

// out[node, 0:64] = log_softmax(a2[node, 0:16] @ W2 + b2). One wave per node.
__global__ __launch_bounds__(256) void k_out(const float* __restrict__ a2,
                                             const float* __restrict__ W2,
                                             const float* __restrict__ b2,
                                             float* __restrict__ out, int n) {
  __shared__ float w[FMID * FOUT];  // 4 KB
  for (int idx = threadIdx.x; idx < FMID * FOUT; idx += 256) w[idx] = W2[idx];
  __syncthreads();
  const int lane = threadIdx.x & 63;
  const int node = blockIdx.x * 4 + (threadIdx.x >> 6);
  if (node >= n) return;
  const float* ar = a2 + (size_t)node * FMID;
  float o = b2[lane];
#pragma unroll
  for (int k = 0; k < FMID; ++k) o += ar[k] * w[k * FOUT + lane];
  float m = o;
#pragma unroll
  for (int off = 32; off >= 1; off >>= 1) m = fmaxf(m, __shfl_xor(m, off));
  float e = __expf(o - m);
  float s = e;
#pragma unroll
  for (int off = 32; off >= 1; off >>= 1) s += __shfl_xor(s, off);
  out[(size_t)node * FOUT + lane] = o - m - __logf(s);
}

// ==================== fallback (atomic path, small ws) ====================

__global__ void k_deg_init(float* __restrict__ deg, int n) {
  int i = blockIdx.x * blockDim.x + threadIdx.x;
  if (i < n) deg[i] = 1.0f;
}
__global__ void k_deg_edges(const int* __restrict__ dst, float* __restrict__ deg, int E) {
  int e = blockIdx.x * blockDim.x + threadIdx.x;
  if (e < E) atomicAdd(&deg[dst[e]], 1.0f);
}
__global__ void k_deg_finish(float* __restrict__ deg, int n) {
  int i = blockIdx.x * blockDim.x + threadIdx.x;
  if (i < n) deg[i] = rsqrtf(deg[i]);
}
__global__ void k_selfloop_s(const float* __restrict__ hs, const float* __restrict__ dis,
                             float* __restrict__ a, int total16) {
  int t = blockIdx.x * blockDim.x + threadIdx.x;
  if (t < total16) a[t] = hs[t] * dis[t >> 4];
}
__global__ void k_prop_atomic(const float* __restrict__ hs, const int* __restrict__ src,
                              const int* __restrict__ dst, const float* __restrict__ dis,
                              float* __restrict__ outp, int E) {
  int t = blockIdx.x * blockDim.x + threadIdx.x;
  int e = t >> 4;
  if (e >= E) return;
  int jj = t & 15;
  int s = src[e], d = dst[e];
  atomicAdd(&outp[(size_t)d * FMID + jj], hs[(size_t)s * FMID + jj] * dis[d]);
}
__global__ void k_bias_relu_s(float* __restrict__ a, const float* __restrict__ b,
                              const float* __restrict__ dis, int total16) {
  int t = blockIdx.x * blockDim.x + threadIdx.x;
  if (t < total16) {
    float v = a[t] + b[t & 15];
    a[t] = (v > 0.f ? v : 0.f) * dis[t >> 4];
  }
}

// ============================ launcher ============================

extern "C" void kernel_launch(void* const* d_in, const int* in_sizes, int n_in,
                              void* d_out, int out_size, void* d_ws, size_t ws_size,
                              hipStream_t stream) {
  const float* x  = (const float*)d_in[0];
  const int* edge = (const int*)d_in[1];
  const float* W1 = (const float*)d_in[2];
  const float* b1 = (const float*)d_in[3];
  const float* W2 = (const float*)d_in[4];
  const float* b2 = (const float*)d_in[5];
  float* out = (float*)d_out;

  const int N = in_sizes[0] / FIN;   // 100000
  const int E = in_sizes[1] / 2;     // 3200000
  const int* src = edge;
  const int* dst = edge + E;

  const int T = 256;
  const int t16n = N * FMID;
  const int ngroups = (N + 3) / 4;
  int gblocks = (ngroups + 3) / 4;
  if (gblocks > 2048) gblocks = 2048;

  // CSR-path workspace: floats dis[N] | buf0[16N] | buf1[16N], then ints
  // cnt[N] | rowstart[N+1] | (unused N) | bsum[512] | csr[E]  (~27 MB)
  // rank[E] aliases buf0..buf1 (32N floats == E ints); dead before k_gemm1.
  size_t need_csr = ((size_t)33 * N + (size_t)3 * N + 1 + 512 + (size_t)E) * 4;

  if (ws_size >= need_csr) {
    float* fbase = (float*)d_ws;
    float* dis  = fbase;
    float* buf0 = fbase + (size_t)N;         // hs, later a2
    float* buf1 = fbase + 17 * (size_t)N;    // a1 (scaled)
    int* rank     = (int*)(fbase + (size_t)N);  // aliases buf0+buf1 (E ints)
    int* ibase    = (int*)(fbase + 33 * (size_t)N);
    int* cnt      = ibase;
    int* rowstart = ibase + N;
    int* bsum     = ibase + 3 * (size_t)N + 1;
    int* csr      = ibase + 3 * (size_t)N + 1 + 512;

    const int NB = (N + 255) / 256;  // 391 <= 512

    hipMemsetAsync(cnt, 0, (size_t)N * sizeof(int), stream);
    k_count   <<<((E + 3) / 4 + T - 1) / T, T, 0, stream>>>(dst, cnt, rank, E);
    k_blocksum<<<NB, 256, 0, stream>>>(cnt, bsum, N);
    k_scanb   <<<1, 512, 0, stream>>>(bsum, NB);
    k_scanf   <<<NB, 256, 0, stream>>>(cnt, bsum, rowstart, dis, N);
    k_scatter <<<((E + 3) / 4 + T - 1) / T, T, 0, stream>>>(src, dst, rank, rowstart, csr, E);

    k_gemm1   <<<gblocks, T, 0, stream>>>(x, W1, dis, buf0, N, ngroups);

    const int PB = (t16n + T - 1) / T;
    k_prop_csr<true>  <<<PB, T, 0, stream>>>(buf0, rowstart, csr, dis, b1, buf1, N);
    k_prop_csr<false> <<<PB, T, 0, stream>>>(buf1, rowstart, csr, dis, b1, buf0, N);
    k_out     <<<(N + 3) / 4, T, 0, stream>>>(buf0, W2, b2, out, N);
  } else {
    // atomic fallback: dis[N] | hs[16N] | a1[16N] | a2[16N] (~19.6 MB)
    float* f   = (float*)d_ws;
    float* dis = f;
    float* hs  = f + (size_t)N;
    float* a1  = f + 17 * (size_t)N;
    float* a2  = f + 33 * (size_t)N;
    const long te = (long)E * FMID;

    k_deg_init  <<<(N + T - 1) / T, T, 0, stream>>>(dis, N);
    k_deg_edges <<<(E + T - 1) / T, T, 0, stream>>>(dst, dis, E);
    k_deg_finish<<<(N + T - 1) / T, T, 0, stream>>>(dis, N);

    k_gemm1     <<<gblocks, T, 0, stream>>>(x, W1, dis, hs, N, ngroups);

    k_selfloop_s<<<(t16n + T - 1) / T, T, 0, stream>>>(hs, dis, a1, t16n);
    k_prop_atomic<<<(int)((te + T - 1) / T), T, 0, stream>>>(hs, src, dst, dis, a1, E);
    k_bias_relu_s<<<(t16n + T - 1) / T, T, 0, stream>>>(a1, b1, dis, t16n);

    k_selfloop_s<<<(t16n + T - 1) / T, T, 0, stream>>>(a1, dis, a2, t16n);
    k_prop_atomic<<<(int)((te + T - 1) / T), T, 0, stream>>>(a1, src, dst, dis, a2, E);

    k_out       <<<(N + 3) / 4, T, 0, stream>>>(a2, W2, b2, out, N);
  }
}

// Round 4
// 721.930 us; speedup vs baseline: 1.0548x; 1.0548x over previous
//
#include <hip/hip_runtime.h>

#define FIN 512
#define FMID 16
#define FOUT 64

// ============================ CSR build ============================

// Count in-degree AND record each edge's rank among same-dst edges.
// 8 edges per thread for ILP (8 independent atomic chains in flight).
__global__ void k_count(const int* __restrict__ dst, int* __restrict__ cnt,
                        int* __restrict__ rank, int E) {
  int t = blockIdx.x * blockDim.x + threadIdx.x;
  int e = t * 8;
  if (e + 7 < E) {
    int4 d0 = *(const int4*)(dst + e);
    int4 d1 = *(const int4*)(dst + e + 4);
    int r0 = atomicAdd(&cnt[d0.x], 1);
    int r1 = atomicAdd(&cnt[d0.y], 1);
    int r2 = atomicAdd(&cnt[d0.z], 1);
    int r3 = atomicAdd(&cnt[d0.w], 1);
    int r4 = atomicAdd(&cnt[d1.x], 1);
    int r5 = atomicAdd(&cnt[d1.y], 1);
    int r6 = atomicAdd(&cnt[d1.z], 1);
    int r7 = atomicAdd(&cnt[d1.w], 1);
    *(int4*)(rank + e)     = make_int4(r0, r1, r2, r3);
    *(int4*)(rank + e + 4) = make_int4(r4, r5, r6, r7);
  } else {
    for (; e < E; ++e) rank[e] = atomicAdd(&cnt[dst[e]], 1);
  }
}

// per-256-chunk sums for the hierarchical exclusive scan
__global__ __launch_bounds__(256) void k_blocksum(const int* __restrict__ cnt,
                                                  int* __restrict__ bsum, int n) {
  __shared__ int sm[4];
  int i = blockIdx.x * 256 + threadIdx.x;
  int v = (i < n) ? cnt[i] : 0;
#pragma unroll
  for (int off = 32; off >= 1; off >>= 1) v += __shfl_xor(v, off);
  if ((threadIdx.x & 63) == 0) sm[threadIdx.x >> 6] = v;
  __syncthreads();
  if (threadIdx.x == 0) bsum[blockIdx.x] = sm[0] + sm[1] + sm[2] + sm[3];
}

// single-block exclusive scan of the (<=512) chunk sums
__global__ __launch_bounds__(512) void k_scanb(int* __restrict__ bsum, int nb) {
  __shared__ int sm[512];
  int t = threadIdx.x;
  int v = (t < nb) ? bsum[t] : 0;
  sm[t] = v;
  __syncthreads();
  for (int off = 1; off < 512; off <<= 1) {
    int add = (t >= off) ? sm[t - off] : 0;
    __syncthreads();
    sm[t] += add;
    __syncthreads();
  }
  if (t < nb) bsum[t] = sm[t] - v;  // exclusive
}

// per-chunk exclusive scan + chunk offset -> rowstart[N+1]; also dis = rsqrt(deg+1)
__global__ __launch_bounds__(256) void k_scanf(const int* __restrict__ cnt,
                                               const int* __restrict__ bsum,
                                               int* __restrict__ rowstart,
                                               float* __restrict__ dis, int n) {
  __shared__ int sm[256];
  int t = threadIdx.x;
  int i = blockIdx.x * 256 + t;
  int v = (i < n) ? cnt[i] : 0;
  sm[t] = v;
  __syncthreads();
  for (int off = 1; off < 256; off <<= 1) {
    int add = (t >= off) ? sm[t - off] : 0;
    __syncthreads();
    sm[t] += add;
    __syncthreads();
  }
  int excl = sm[t] - v + bsum[blockIdx.x];
  if (i < n) {
    rowstart[i] = excl;
    dis[i] = rsqrtf((float)v + 1.0f);  // +1 self-loop
  }
  if (i == n - 1) rowstart[n] = excl + v;  // total = E
}

// Atomic-free scatter: position is rowstart[dst] + rank. Pure stores, no RMW.
__global__ void k_scatter(const int* __restrict__ src, const int* __restrict__ dst,
                          const int* __restrict__ rank, const int* __restrict__ rowstart,
                          int* __restrict__ csr_src, int E) {
  int t = blockIdx.x * blockDim.x + threadIdx.x;
  int e = t * 4;
  if (e + 3 < E) {
    int4 s = *(const int4*)(src + e);
    int4 d = *(const int4*)(dst + e);
    int4 r = *(const int4*)(rank + e);
    csr_src[rowstart[d.x] + r.x] = s.x;
    csr_src[rowstart[d.y] + r.y] = s.y;
    csr_src[rowstart[d.z] + r.z] = s.z;
    csr_src[rowstart[d.w] + r.w] = s.w;
  } else {
    for (; e < E; ++e) csr_src[rowstart[dst[e]] + rank[e]] = src[e];
  }
}

// ============================ dense layers ============================

// Stage one 16-row x tile into LDS via global_load_lds (1 KB/inst, coalesced).
// Wave wid stages its own 4 rows (2 segments of 1 KB each). LDS dest is LINEAR
// (wave-uniform base + lane*16, HW rule); the bank-decorrelating swizzle
// P = B ^ ((B>>5)&3) ^ r (float4-block index B within the row, r = row&3) is
// applied on the GLOBAL SOURCE address (involution; read side applies the same
// XOR). This makes the 4 k-quarter reads (stride 128 floats = bank-aliased)
// land in 4 distinct bank-quads, and decorrelates the 4 rows too.
__device__ __forceinline__ void stage_tile(const float* __restrict__ x,
                                           float* lbuf, int tile, int n,
                                           int wid, int lane) {
#pragma unroll
  for (int r = 0; r < 4; ++r) {
    int row = tile * 16 + wid * 4 + r;
    int rowc = row < n ? row : (n - 1);
    const float* gr = x + (size_t)rowc * FIN;
#pragma unroll
    for (int seg = 0; seg < 2; ++seg) {
      int Blin = seg * 64 + lane;
      int Blog = Blin ^ ((Blin >> 5) & 3) ^ r;
      const float* g = gr + (Blog << 2);
      float* l = lbuf + (wid * 4 + r) * FIN + seg * 256;  // wave-uniform
      __builtin_amdgcn_global_load_lds(
          (const __attribute__((address_space(1))) void*)g,
          (__attribute__((address_space(3))) void*)l, 16, 0, 0);
    }
  }
}

// hs[node, 0:16] = (x[node, 0:512] @ W1) * dis[node].
// Double-buffered LDS pipeline: block = 16-node tile; while computing tile t
// from LDS, the next tile's rows stream in via global_load_lds (issued before
// compute, drained by the implicit vmcnt(0) at __syncthreads — T3 minimum
// 2-phase). Fixes round-3's latency wall: the old per-lane x loads were
// 64 B/wave-inst lane-uniform gathers (1 L1-miss line per ~37 cyc, MSHR-bound,
// 191 us); DMA staging moves 1 KB/inst at streaming rate.
// Compute: lane = q*16+j (q = k-quarter, j = output); per t4 one swizzled
// w-read + 4 broadcast x-row reads feed 16 FMAs.
__global__ __launch_bounds__(256) void k_gemm1(const float* __restrict__ x,
                                               const float* __restrict__ W1,
                                               const float* __restrict__ dis,
                                               float* __restrict__ hs, int n,
                                               int ntiles) {
  __shared__ float wt[FMID * FIN];   // 32 KB transposed + j-swizzled W1
  __shared__ float xb[2][16 * FIN];  // 2 x 32 KB x tiles
  for (int idx = threadIdx.x; idx < FIN * FMID; idx += 256) {
    int j = idx >> 9, k = idx & 511;
    wt[(j << 9) | (k ^ ((j & 7) << 2))] = W1[k * FMID + j];
  }
  const int lane = threadIdx.x & 63;
  const int wid  = threadIdx.x >> 6;
  const int q = lane >> 4, j = lane & 15;
  const int jsw = (j & 7) << 2;
  const float* wrow = wt + (j << 9);

  int tile = blockIdx.x;
  if (tile < ntiles) stage_tile(x, xb[0], tile, n, wid, lane);
  __syncthreads();  // drains prologue DMA (vmcnt 0) + wt writes
  int cur = 0;
  for (; tile < ntiles; tile += gridDim.x) {
    int nxt = tile + gridDim.x;
    if (nxt < ntiles) stage_tile(x, xb[cur ^ 1], nxt, n, wid, lane);

    const float* xw = xb[cur] + (wid * 4) * FIN + q * 128;
    float a0 = 0.f, a1 = 0.f, a2 = 0.f, a3 = 0.f;
#pragma unroll 4
    for (int t4 = 0; t4 < 32; ++t4) {
      float4 w4 = *(const float4*)(wrow + ((q * 128 + t4 * 4) ^ jsw));
      int p = t4 ^ q;
      float4 v0 = *(const float4*)(xw +            ((p ^ 0) << 2));
      float4 v1 = *(const float4*)(xw + 1 * FIN + ((p ^ 1) << 2));
      float4 v2 = *(const float4*)(xw + 2 * FIN + ((p ^ 2) << 2));
      float4 v3 = *(const float4*)(xw + 3 * FIN + ((p ^ 3) << 2));
      a0 += v0.x * w4.x + v0.y * w4.y + v0.z * w4.z + v0.w * w4.w;
      a1 += v1.x * w4.x + v1.y * w4.y + v1.z * w4.z + v1.w * w4.w;
      a2 += v2.x * w4.x + v2.y * w4.y + v2.z * w4.z + v2.w * w4.w;
      a3 += v3.x * w4.x + v3.y * w4.y + v3.z * w4.z + v3.w * w4.w;
    }
    a0 += __shfl_xor(a0, 16); a0 += __shfl_xor(a0, 32);
    a1 += __shfl_xor(a1, 16); a1 += __shfl_xor(a1, 32);
    a2 += __shfl_xor(a2, 16); a2 += __shfl_xor(a2, 32);
    a3 += __shfl_xor(a3, 16); a3 += __shfl_xor(a3, 32);
    const int node0 = tile * 16 + wid * 4;
    if (lane < FMID) {
      if (node0     < n) hs[(size_t)(node0    ) * FMID + j] = a0 * dis[node0];
      if (node0 + 1 < n) hs[(size_t)(node0 + 1) * FMID + j] = a1 * dis[node0 + 1];
      if (node0 + 2 < n) hs[(size_t)(node0 + 2) * FMID + j] = a2 * dis[node0 + 2];
      if (node0 + 3 < n) hs[(size_t)(node0 + 3) * FMID + j] = a3 * dis[node0 + 3];
    }
    __syncthreads();  // next tile's DMA done; all waves finished reading cur
    cur ^= 1;
  }
}

// CSR gather propagation, float4 rows. 16 lanes per node, split into 4
// subgroups of 4 lanes; subgroup g handles edge slot g, lane-in-subgroup c
// owns features [4c, 4c+4). Per 16-edge batch: one coalesced index load,
// then 16 float4 row-gathers (4 per lane). End: reduce across subgroups.
// Input hs is pre-scaled by dis[src]:
//   raw[d][j] = dis[d] * (hs[d][j] + sum_{s in N(d)} hs[s][j])
// RELU=true (layer 1): out = relu(raw + bias) * dis[d]   (pre-scaled for layer 2)
// RELU=false (layer 2): out = raw                        (k_out adds b2)
template <bool RELU>
__global__ __launch_bounds__(256) void k_prop_csr(const float* __restrict__ hs,
                                                  const int* __restrict__ rowstart,
                                                  const int* __restrict__ csr,
                                                  const float* __restrict__ dis,
                                                  const float* __restrict__ bias,
                                                  float* __restrict__ outp, int n) {
  int t = blockIdx.x * blockDim.x + threadIdx.x;
  int node = t >> 4;
  if (node >= n) return;
  const int j = t & 15;   // lane within 16-group
  const int g = j >> 2;   // subgroup (edge slot)
  const int c = j & 3;    // float4 column
  int beg = rowstart[node], end = rowstart[node + 1];
  float4 acc = make_float4(0.f, 0.f, 0.f, 0.f);
  if (g == 0) {  // self-loop term (already dis[src]-scaled)
    float4 v = ((const float4*)(hs + (size_t)node * FMID))[c];
    acc.x += v.x; acc.y += v.y; acc.z += v.z; acc.w += v.w;
  }
  int i = beg;
  int stop = beg + ((end - beg) & ~15);
  for (; i < stop; i += 16) {
    int sv = csr[i + j];
#pragma unroll
    for (int k = 0; k < 4; ++k) {
      int sidx = __shfl(sv, k * 4 + g, 16);
      float4 v = ((const float4*)(hs + (size_t)sidx * FMID))[c];
      acc.x += v.x; acc.y += v.y; acc.z += v.z; acc.w += v.w;
    }
  }
  // remainder: one edge per step, round-robin over subgroups
  for (int u = 0; i < end; ++i, ++u) {
    int sidx = csr[i];  // uniform within group -> broadcast
    if (g == (u & 3)) {
      float4 v = ((const float4*)(hs + (size_t)sidx * FMID))[c];
      acc.x += v.x; acc.y += v.y; acc.z += v.z; acc.w += v.w;
    }
  }
  // reduce across subgroups (lanes differing in bits 2..3)
#pragma unroll
  for (int off = 4; off <= 8; off <<= 1) {
    acc.x += __shfl_xor(acc.x, off, 16);
    acc.y += __shfl_xor(acc.y, off, 16);
    acc.z += __shfl_xor(acc.z, off, 16);
    acc.w += __shfl_xor(acc.w, off, 16);
  }
  if (g == 0) {
    float dd = dis[node];
    float4 r;
    r.x = dd * acc.x; r.y = dd * acc.y; r.z = dd * acc.z; r.w = dd * acc.w;
    if (RELU) {
      float4 bb = ((const float4*)bias)[c];
      r.x = fmaxf(r.x + bb.x, 0.f) * dd;
      r.y = fmaxf(r.y + bb.y, 0.f) * dd;
      r.z = fmaxf(r.z + bb.z, 0.f) * dd;
      r.w = fmaxf(r.w + bb.w, 0.f) * dd;
    }
    ((float4*)(outp + (size_t)node * FMID))[c] = r;
  }
}

// out[node, 0:64] = log_softmax(a2[node, 0:16] @ W2 + b2). One wave per node.
__global__ __launch_bounds__(256) void k_out(const float* __restrict__ a2,
                                             const float* __restrict__ W2,
                                             const float* __restrict__ b2,
                                             float* __restrict__ out, int n) {
  __shared__ float w[FMID * FOUT];  // 4 KB
  for (int idx = threadIdx.x; idx < FMID * FOUT; idx += 256) w[idx] = W2[idx];
  __syncthreads();
  const int lane = threadIdx.x & 63;
  const int node = blockIdx.x * 4 + (threadIdx.x >> 6);
  if (node >= n) return;
  const float* ar = a2 + (size_t)node * FMID;
  float o = b2[lane];
#pragma unroll
  for (int k = 0; k < FMID; ++k) o += ar[k] * w[k * FOUT + lane];
  float m = o;
#pragma unroll
  for (int off = 32; off >= 1; off >>= 1) m = fmaxf(m, __shfl_xor(m, off));
  float e = __expf(o - m);
  float s = e;
#pragma unroll
  for (int off = 32; off >= 1; off >>= 1) s += __shfl_xor(s, off);
  out[(size_t)node * FOUT + lane] = o - m - __logf(s);
}

// ==================== fallback (atomic path, small ws) ====================

__global__ void k_deg_init(float* __restrict__ deg, int n) {
  int i = blockIdx.x * blockDim.x + threadIdx.x;
  if (i < n) deg[i] = 1.0f;
}
__global__ void k_deg_edges(const int* __restrict__ dst, float* __restrict__ deg, int E) {
  int e = blockIdx.x * blockDim.x + threadIdx.x;
  if (e < E) atomicAdd(&deg[dst[e]], 1.0f);
}
__global__ void k_deg_finish(float* __restrict__ deg, int n) {
  int i = blockIdx.x * blockDim.x + threadIdx.x;
  if (i < n) deg[i] = rsqrtf(deg[i]);
}
__global__ void k_selfloop_s(const float* __restrict__ hs, const float* __restrict__ dis,
                             float* __restrict__ a, int total16) {
  int t = blockIdx.x * blockDim.x + threadIdx.x;
  if (t < total16) a[t] = hs[t] * dis[t >> 4];
}
__global__ void k_prop_atomic(const float* __restrict__ hs, const int* __restrict__ src,
                              const int* __restrict__ dst, const float* __restrict__ dis,
                              float* __restrict__ outp, int E) {
  int t = blockIdx.x * blockDim.x + threadIdx.x;
  int e = t >> 4;
  if (e >= E) return;
  int jj = t & 15;
  int s = src[e], d = dst[e];
  atomicAdd(&outp[(size_t)d * FMID + jj], hs[(size_t)s * FMID + jj] * dis[d]);
}
__global__ void k_bias_relu_s(float* __restrict__ a, const float* __restrict__ b,
                              const float* __restrict__ dis, int total16) {
  int t = blockIdx.x * blockDim.x + threadIdx.x;
  if (t < total16) {
    float v = a[t] + b[t & 15];
    a[t] = (v > 0.f ? v : 0.f) * dis[t >> 4];
  }
}

// ============================ launcher ============================

extern "C" void kernel_launch(void* const* d_in, const int* in_sizes, int n_in,
                              void* d_out, int out_size, void* d_ws, size_t ws_size,
                              hipStream_t stream) {
  const float* x  = (const float*)d_in[0];
  const int* edge = (const int*)d_in[1];
  const float* W1 = (const float*)d_in[2];
  const float* b1 = (const float*)d_in[3];
  const float* W2 = (const float*)d_in[4];
  const float* b2 = (const float*)d_in[5];
  float* out = (float*)d_out;

  const int N = in_sizes[0] / FIN;   // 100000
  const int E = in_sizes[1] / 2;     // 3200000
  const int* src = edge;
  const int* dst = edge + E;

  const int T = 256;
  const int t16n = N * FMID;
  const int ntiles = (N + 15) / 16;  // 6250
  int gblocks = ntiles < 1024 ? ntiles : 1024;

  // CSR-path workspace: floats dis[N] | buf0[16N] | buf1[16N], then ints
  // cnt[N] | rowstart[N+1] | (unused N) | bsum[512] | csr[E]  (~27 MB)
  // rank[E] aliases buf0..buf1 (32N floats == E ints); dead before k_gemm1.
  size_t need_csr = ((size_t)33 * N + (size_t)3 * N + 1 + 512 + (size_t)E) * 4;

  if (ws_size >= need_csr) {
    float* fbase = (float*)d_ws;
    float* dis  = fbase;
    float* buf0 = fbase + (size_t)N;         // hs, later a2
    float* buf1 = fbase + 17 * (size_t)N;    // a1 (scaled)
    int* rank     = (int*)(fbase + (size_t)N);  // aliases buf0+buf1 (E ints)
    int* ibase    = (int*)(fbase + 33 * (size_t)N);
    int* cnt      = ibase;
    int* rowstart = ibase + N;
    int* bsum     = ibase + 3 * (size_t)N + 1;
    int* csr      = ibase + 3 * (size_t)N + 1 + 512;

    const int NB = (N + 255) / 256;  // 391 <= 512

    hipMemsetAsync(cnt, 0, (size_t)N * sizeof(int), stream);
    k_count   <<<((E + 7) / 8 + T - 1) / T, T, 0, stream>>>(dst, cnt, rank, E);
    k_blocksum<<<NB, 256, 0, stream>>>(cnt, bsum, N);
    k_scanb   <<<1, 512, 0, stream>>>(bsum, NB);
    k_scanf   <<<NB, 256, 0, stream>>>(cnt, bsum, rowstart, dis, N);
    k_scatter <<<((E + 3) / 4 + T - 1) / T, T, 0, stream>>>(src, dst, rank, rowstart, csr, E);

    k_gemm1   <<<gblocks, T, 0, stream>>>(x, W1, dis, buf0, N, ntiles);

    const int PB = (t16n + T - 1) / T;
    k_prop_csr<true>  <<<PB, T, 0, stream>>>(buf0, rowstart, csr, dis, b1, buf1, N);
    k_prop_csr<false> <<<PB, T, 0, stream>>>(buf1, rowstart, csr, dis, b1, buf0, N);
    k_out     <<<(N + 3) / 4, T, 0, stream>>>(buf0, W2, b2, out, N);
  } else {
    // atomic fallback: dis[N] | hs[16N] | a1[16N] | a2[16N] (~19.6 MB)
    float* f   = (float*)d_ws;
    float* dis = f;
    float* hs  = f + (size_t)N;
    float* a1  = f + 17 * (size_t)N;
    float* a2  = f + 33 * (size_t)N;
    const long te = (long)E * FMID;

    k_deg_init  <<<(N + T - 1) / T, T, 0, stream>>>(dis, N);
    k_deg_edges <<<(E + T - 1) / T, T, 0, stream>>>(dst, dis, E);
    k_deg_finish<<<(N + T - 1) / T, T, 0, stream>>>(dis, N);

    k_gemm1     <<<gblocks, T, 0, stream>>>(x, W1, dis, hs, N, ntiles);

    k_selfloop_s<<<(t16n + T - 1) / T, T, 0, stream>>>(hs, dis, a1, t16n);
    k_prop_atomic<<<(int)((te + T - 1) / T), T, 0, stream>>>(hs, src, dst, dis, a1, E);
    k_bias_relu_s<<<(t16n + T - 1) / T, T, 0, stream>>>(a1, b1, dis, t16n);

    k_selfloop_s<<<(t16n + T - 1) / T, T, 0, stream>>>(a1, dis, a2, t16n);
    k_prop_atomic<<<(int)((te + T - 1) / T), T, 0, stream>>>(a1, src, dst, dis, a2, E);

    k_out       <<<(N + 3) / 4, T, 0, stream>>>(a2, W2, b2, out, N);
  }
}

// Round 5
// 665.263 us; speedup vs baseline: 1.1446x; 1.0852x over previous
//
#include <hip/hip_runtime.h>

#define FIN 512
#define FMID 16
#define FOUT 64

typedef __attribute__((ext_vector_type(8))) short bf8_t;    // 8 x bf16 (4 VGPR)
typedef __attribute__((ext_vector_type(4))) float f32x4_t;  // MFMA acc

__device__ __forceinline__ unsigned short f2bf_rne(float f) {
  unsigned u = __float_as_uint(f);
  return (unsigned short)((u + 0x7FFFu + ((u >> 16) & 1u)) >> 16);
}
__device__ __forceinline__ float bf2f(unsigned short h) {
  return __uint_as_float(((unsigned)h) << 16);
}

// ============================ CSR build ============================

// Count in-degree AND record each edge's rank among same-dst edges.
// 8 edges per thread for ILP (8 independent atomic chains in flight).
__global__ void k_count(const int* __restrict__ dst, int* __restrict__ cnt,
                        int* __restrict__ rank, int E) {
  int t = blockIdx.x * blockDim.x + threadIdx.x;
  int e = t * 8;
  if (e + 7 < E) {
    int4 d0 = *(const int4*)(dst + e);
    int4 d1 = *(const int4*)(dst + e + 4);
    int r0 = atomicAdd(&cnt[d0.x], 1);
    int r1 = atomicAdd(&cnt[d0.y], 1);
    int r2 = atomicAdd(&cnt[d0.z], 1);
    int r3 = atomicAdd(&cnt[d0.w], 1);
    int r4 = atomicAdd(&cnt[d1.x], 1);
    int r5 = atomicAdd(&cnt[d1.y], 1);
    int r6 = atomicAdd(&cnt[d1.z], 1);
    int r7 = atomicAdd(&cnt[d1.w], 1);
    *(int4*)(rank + e)     = make_int4(r0, r1, r2, r3);
    *(int4*)(rank + e + 4) = make_int4(r4, r5, r6, r7);
  } else {
    for (; e < E; ++e) rank[e] = atomicAdd(&cnt[dst[e]], 1);
  }
}

// per-256-chunk sums for the hierarchical exclusive scan
__global__ __launch_bounds__(256) void k_blocksum(const int* __restrict__ cnt,
                                                  int* __restrict__ bsum, int n) {
  __shared__ int sm[4];
  int i = blockIdx.x * 256 + threadIdx.x;
  int v = (i < n) ? cnt[i] : 0;
#pragma unroll
  for (int off = 32; off >= 1; off >>= 1) v += __shfl_xor(v, off);
  if ((threadIdx.x & 63) == 0) sm[threadIdx.x >> 6] = v;
  __syncthreads();
  if (threadIdx.x == 0) bsum[blockIdx.x] = sm[0] + sm[1] + sm[2] + sm[3];
}

// single-block exclusive scan of the (<=512) chunk sums
__global__ __launch_bounds__(512) void k_scanb(int* __restrict__ bsum, int nb) {
  __shared__ int sm[512];
  int t = threadIdx.x;
  int v = (t < nb) ? bsum[t] : 0;
  sm[t] = v;
  __syncthreads();
  for (int off = 1; off < 512; off <<= 1) {
    int add = (t >= off) ? sm[t - off] : 0;
    __syncthreads();
    sm[t] += add;
    __syncthreads();
  }
  if (t < nb) bsum[t] = sm[t] - v;  // exclusive
}

// per-chunk exclusive scan + chunk offset -> rowstart[N+1]; also dis = rsqrt(deg+1)
__global__ __launch_bounds__(256) void k_scanf(const int* __restrict__ cnt,
                                               const int* __restrict__ bsum,
                                               int* __restrict__ rowstart,
                                               float* __restrict__ dis, int n) {
  __shared__ int sm[256];
  int t = threadIdx.x;
  int i = blockIdx.x * 256 + t;
  int v = (i < n) ? cnt[i] : 0;
  sm[t] = v;
  __syncthreads();
  for (int off = 1; off < 256; off <<= 1) {
    int add = (t >= off) ? sm[t - off] : 0;
    __syncthreads();
    sm[t] += add;
    __syncthreads();
  }
  int excl = sm[t] - v + bsum[blockIdx.x];
  if (i < n) {
    rowstart[i] = excl;
    dis[i] = rsqrtf((float)v + 1.0f);  // +1 self-loop
  }
  if (i == n - 1) rowstart[n] = excl + v;  // total = E
}

// Atomic-free scatter: position is rowstart[dst] + rank. Pure stores, no RMW.
__global__ void k_scatter(const int* __restrict__ src, const int* __restrict__ dst,
                          const int* __restrict__ rank, const int* __restrict__ rowstart,
                          int* __restrict__ csr_src, int E) {
  int t = blockIdx.x * blockDim.x + threadIdx.x;
  int e = t * 4;
  if (e + 3 < E) {
    int4 s = *(const int4*)(src + e);
    int4 d = *(const int4*)(dst + e);
    int4 r = *(const int4*)(rank + e);
    csr_src[rowstart[d.x] + r.x] = s.x;
    csr_src[rowstart[d.y] + r.y] = s.y;
    csr_src[rowstart[d.z] + r.z] = s.z;
    csr_src[rowstart[d.w] + r.w] = s.w;
  } else {
    for (; e < E; ++e) csr_src[rowstart[dst[e]] + rank[e]] = src[e];
  }
}

// ============================ dense layers ============================

// hs[node,0:16] = (x[node,0:512] @ W1) * dis[node] via mfma_f32_16x16x32_bf16.
// One wave per 16-node tile; fp32 accuracy via split-bf16: x = hi + lo,
// h = hi*Whi + lo*Whi + hi*Wlo (error ~2^-16 rel; lo*lo dropped).
// Fragment maps (m89-verified family): A[lane&15][(lane>>4)*8+i],
// B[(lane>>4)*8+i][lane&15], D row=(lane>>4)*4+r col=lane&15.
// W1 pre-split hi/lo into B-frag order in LDS (lane-stride 16 B ->
// conflict-free ds_read_b128). x read straight from global in frag order:
// each wave-load touches 32 full 64B lines (1 KB unique) -> streaming-rate.
// No per-iteration barrier; waves independent. Replaces round-4's
// broadcast-LDS scalar-FMA loop (640 LDS insts/tile, 1 blk/CU, 152 us).
__global__ __launch_bounds__(256) void k_gemm1(const float* __restrict__ x,
                                               const float* __restrict__ W1,
                                               const float* __restrict__ dis,
                                               float* __restrict__ hs, int n,
                                               int ntiles) {
  __shared__ short wb_hi[16][64][8];  // 16 KB: B-frag hi, [kstep][lane][i]
  __shared__ short wb_lo[16][64][8];  // 16 KB: B-frag lo
  for (int e = threadIdx.x; e < FIN * FMID; e += 256) {
    int k = e >> 4, j = e & 15;
    int ks = k >> 5, kk = k & 31;
    int L = ((kk >> 3) << 4) + j, i = kk & 7;
    float f = W1[e];
    unsigned short h = f2bf_rne(f);
    wb_hi[ks][L][i] = (short)h;
    wb_lo[ks][L][i] = (short)f2bf_rne(f - bf2f(h));
  }
  __syncthreads();
  const int lane = threadIdx.x & 63;
  const int wid  = threadIdx.x >> 6;
  const int rloc = lane & 15;  // A-row / D-col
  const int q    = lane >> 4;  // k-subchunk / D-row-quad
  for (int tile = blockIdx.x * 4 + wid; tile < ntiles; tile += gridDim.x * 4) {
    int row = tile * 16 + rloc;
    const float4* xr = (const float4*)(x + (size_t)(row < n ? row : n - 1) * FIN);
    f32x4_t acc = {0.f, 0.f, 0.f, 0.f};
#pragma unroll 4
    for (int ks = 0; ks < 16; ++ks) {
      float4 v0 = xr[ks * 8 + q * 2];
      float4 v1 = xr[ks * 8 + q * 2 + 1];
      float fv[8] = {v0.x, v0.y, v0.z, v0.w, v1.x, v1.y, v1.z, v1.w};
      bf8_t ah, al;
#pragma unroll
      for (int i = 0; i < 8; ++i) {
        unsigned short h = f2bf_rne(fv[i]);
        ah[i] = (short)h;
        al[i] = (short)f2bf_rne(fv[i] - bf2f(h));
      }
      bf8_t bh = *(const bf8_t*)&wb_hi[ks][lane][0];
      bf8_t bl = *(const bf8_t*)&wb_lo[ks][lane][0];
      acc = __builtin_amdgcn_mfma_f32_16x16x32_bf16(ah, bh, acc, 0, 0, 0);
      acc = __builtin_amdgcn_mfma_f32_16x16x32_bf16(al, bh, acc, 0, 0, 0);
      acc = __builtin_amdgcn_mfma_f32_16x16x32_bf16(ah, bl, acc, 0, 0, 0);
    }
    int nb = tile * 16 + q * 4;
#pragma unroll
    for (int r = 0; r < 4; ++r) {
      int node = nb + r;
      if (node < n) hs[(size_t)node * FMID + rloc] = acc[r] * dis[node];
    }
  }
}

// CSR gather propagation, float4 rows. 16 lanes per node, split into 4
// subgroups of 4 lanes; subgroup g handles edge slot g, lane-in-subgroup c
// owns features [4c, 4c+4). Per 16-edge batch: one coalesced index load,
// then 16 float4 row-gathers (4 per lane). End: reduce across subgroups.
// Input hs is pre-scaled by dis[src]:
//   raw[d][j] = dis[d] * (hs[d][j] + sum_{s in N(d)} hs[s][j])
// RELU=true (layer 1): out = relu(raw + bias) * dis[d]   (pre-scaled for layer 2)
// RELU=false (layer 2): out = raw                        (k_out adds b2)
template <bool RELU>
__global__ __launch_bounds__(256) void k_prop_csr(const float* __restrict__ hs,
                                                  const int* __restrict__ rowstart,
                                                  const int* __restrict__ csr,
                                                  const float* __restrict__ dis,
                                                  const float* __restrict__ bias,
                                                  float* __restrict__ outp, int n) {
  int t = blockIdx.x * blockDim.x + threadIdx.x;
  int node = t >> 4;
  if (node >= n) return;
  const int j = t & 15;   // lane within 16-group
  const int g = j >> 2;   // subgroup (edge slot)
  const int c = j & 3;    // float4 column
  int beg = rowstart[node], end = rowstart[node + 1];
  float4 acc = make_float4(0.f, 0.f, 0.f, 0.f);
  if (g == 0) {  // self-loop term (already dis[src]-scaled)
    float4 v = ((const float4*)(hs + (size_t)node * FMID))[c];
    acc.x += v.x; acc.y += v.y; acc.z += v.z; acc.w += v.w;
  }
  int i = beg;
  int stop = beg + ((end - beg) & ~15);
  for (; i < stop; i += 16) {
    int sv = csr[i + j];
#pragma unroll
    for (int k = 0; k < 4; ++k) {
      int sidx = __shfl(sv, k * 4 + g, 16);
      float4 v = ((const float4*)(hs + (size_t)sidx * FMID))[c];
      acc.x += v.x; acc.y += v.y; acc.z += v.z; acc.w += v.w;
    }
  }
  // remainder: one edge per step, round-robin over subgroups
  for (int u = 0; i < end; ++i, ++u) {
    int sidx = csr[i];  // uniform within group -> broadcast
    if (g == (u & 3)) {
      float4 v = ((const float4*)(hs + (size_t)sidx * FMID))[c];
      acc.x += v.x; acc.y += v.y; acc.z += v.z; acc.w += v.w;
    }
  }
  // reduce across subgroups (lanes differing in bits 2..3)
#pragma unroll
  for (int off = 4; off <= 8; off <<= 1) {
    acc.x += __shfl_xor(acc.x, off, 16);
    acc.y += __shfl_xor(acc.y, off, 16);
    acc.z += __shfl_xor(acc.z, off, 16);
    acc.w += __shfl_xor(acc.w, off, 16);
  }
  if (g == 0) {
    float dd = dis[node];
    float4 r;
    r.x = dd * acc.x; r.y = dd * acc.y; r.z = dd * acc.z; r.w = dd * acc.w;
    if (RELU) {
      float4 bb = ((const float4*)bias)[c];
      r.x = fmaxf(r.x + bb.x, 0.f) * dd;
      r.y = fmaxf(r.y + bb.y, 0.f) * dd;
      r.z = fmaxf(r.z + bb.z, 0.f) * dd;
      r.w = fmaxf(r.w + bb.w, 0.f) * dd;
    }
    ((float4*)(outp + (size_t)node * FMID))[c] = r;
  }
}

// out[node, 0:64] = log_softmax(a2[node, 0:16] @ W2 + b2). One wave per node.
__global__ __launch_bounds__(256) void k_out(const float* __restrict__ a2,
                                             const float* __restrict__ W2,
                                             const float* __restrict__ b2,
                                             float* __restrict__ out, int n) {
  __shared__ float w[FMID * FOUT];  // 4 KB
  for (int idx = threadIdx.x; idx < FMID * FOUT; idx += 256) w[idx] = W2[idx];
  __syncthreads();
  const int lane = threadIdx.x & 63;
  const int node = blockIdx.x * 4 + (threadIdx.x >> 6);
  if (node >= n) return;
  const float* ar = a2 + (size_t)node * FMID;
  float o = b2[lane];
#pragma unroll
  for (int k = 0; k < FMID; ++k) o += ar[k] * w[k * FOUT + lane];
  float m = o;
#pragma unroll
  for (int off = 32; off >= 1; off >>= 1) m = fmaxf(m, __shfl_xor(m, off));
  float e = __expf(o - m);
  float s = e;
#pragma unroll
  for (int off = 32; off >= 1; off >>= 1) s += __shfl_xor(s, off);
  out[(size_t)node * FOUT + lane] = o - m - __logf(s);
}

// ==================== fallback (atomic path, small ws) ====================

__global__ void k_deg_init(float* __restrict__ deg, int n) {
  int i = blockIdx.x * blockDim.x + threadIdx.x;
  if (i < n) deg[i] = 1.0f;
}
__global__ void k_deg_edges(const int* __restrict__ dst, float* __restrict__ deg, int E) {
  int e = blockIdx.x * blockDim.x + threadIdx.x;
  if (e < E) atomicAdd(&deg[dst[e]], 1.0f);
}
__global__ void k_deg_finish(float* __restrict__ deg, int n) {
  int i = blockIdx.x * blockDim.x + threadIdx.x;
  if (i < n) deg[i] = rsqrtf(deg[i]);
}
__global__ void k_selfloop_s(const float* __restrict__ hs, const float* __restrict__ dis,
                             float* __restrict__ a, int total16) {
  int t = blockIdx.x * blockDim.x + threadIdx.x;
  if (t < total16) a[t] = hs[t] * dis[t >> 4];
}
__global__ void k_prop_atomic(const float* __restrict__ hs, const int* __restrict__ src,
                              const int* __restrict__ dst, const float* __restrict__ dis,
                              float* __restrict__ outp, int E) {
  int t = blockIdx.x * blockDim.x + threadIdx.x;
  int e = t >> 4;
  if (e >= E) return;
  int jj = t & 15;
  int s = src[e], d = dst[e];
  atomicAdd(&outp[(size_t)d * FMID + jj], hs[(size_t)s * FMID + jj] * dis[d]);
}
__global__ void k_bias_relu_s(float* __restrict__ a, const float* __restrict__ b,
                              const float* __restrict__ dis, int total16) {
  int t = blockIdx.x * blockDim.x + threadIdx.x;
  if (t < total16) {
    float v = a[t] + b[t & 15];
    a[t] = (v > 0.f ? v : 0.f) * dis[t >> 4];
  }
}

// ============================ launcher ============================

extern "C" void kernel_launch(void* const* d_in, const int* in_sizes, int n_in,
                              void* d_out, int out_size, void* d_ws, size_t ws_size,
                              hipStream_t stream) {
  const float* x  = (const float*)d_in[0];
  const int* edge = (const int*)d_in[1];
  const float* W1 = (const float*)d_in[2];
  const float* b1 = (const float*)d_in[3];
  const float* W2 = (const float*)d_in[4];
  const float* b2 = (const float*)d_in[5];
  float* out = (float*)d_out;

  const int N = in_sizes[0] / FIN;   // 100000
  const int E = in_sizes[1] / 2;     // 3200000
  const int* src = edge;
  const int* dst = edge + E;

  const int T = 256;
  const int t16n = N * FMID;
  const int ntiles = (N + 15) / 16;  // 6250
  int gblocks = (ntiles + 3) / 4;
  if (gblocks > 2048) gblocks = 2048;

  // CSR-path workspace: floats dis[N] | buf0[16N] | buf1[16N], then ints
  // cnt[N] | rowstart[N+1] | (unused N) | bsum[512] | csr[E]  (~27 MB)
  // rank[E] aliases buf0..buf1 (32N floats == E ints); dead before k_gemm1.
  size_t need_csr = ((size_t)33 * N + (size_t)3 * N + 1 + 512 + (size_t)E) * 4;

  if (ws_size >= need_csr) {
    float* fbase = (float*)d_ws;
    float* dis  = fbase;
    float* buf0 = fbase + (size_t)N;         // hs, later a2
    float* buf1 = fbase + 17 * (size_t)N;    // a1 (scaled)
    int* rank     = (int*)(fbase + (size_t)N);  // aliases buf0+buf1 (E ints)
    int* ibase    = (int*)(fbase + 33 * (size_t)N);
    int* cnt      = ibase;
    int* rowstart = ibase + N;
    int* bsum     = ibase + 3 * (size_t)N + 1;
    int* csr      = ibase + 3 * (size_t)N + 1 + 512;

    const int NB = (N + 255) / 256;  // 391 <= 512

    hipMemsetAsync(cnt, 0, (size_t)N * sizeof(int), stream);
    k_count   <<<((E + 7) / 8 + T - 1) / T, T, 0, stream>>>(dst, cnt, rank, E);
    k_blocksum<<<NB, 256, 0, stream>>>(cnt, bsum, N);
    k_scanb   <<<1, 512, 0, stream>>>(bsum, NB);
    k_scanf   <<<NB, 256, 0, stream>>>(cnt, bsum, rowstart, dis, N);
    k_scatter <<<((E + 3) / 4 + T - 1) / T, T, 0, stream>>>(src, dst, rank, rowstart, csr, E);

    k_gemm1   <<<gblocks, T, 0, stream>>>(x, W1, dis, buf0, N, ntiles);

    const int PB = (t16n + T - 1) / T;
    k_prop_csr<true>  <<<PB, T, 0, stream>>>(buf0, rowstart, csr, dis, b1, buf1, N);
    k_prop_csr<false> <<<PB, T, 0, stream>>>(buf1, rowstart, csr, dis, b1, buf0, N);
    k_out     <<<(N + 3) / 4, T, 0, stream>>>(buf0, W2, b2, out, N);
  } else {
    // atomic fallback: dis[N] | hs[16N] | a1[16N] | a2[16N] (~19.6 MB)
    float* f   = (float*)d_ws;
    float* dis = f;
    float* hs  = f + (size_t)N;
    float* a1  = f + 17 * (size_t)N;
    float* a2  = f + 33 * (size_t)N;
    const long te = (long)E * FMID;

    k_deg_init  <<<(N + T - 1) / T, T, 0, stream>>>(dis, N);
    k_deg_edges <<<(E + T - 1) / T, T, 0, stream>>>(dst, dis, E);
    k_deg_finish<<<(N + T - 1) / T, T, 0, stream>>>(dis, N);

    k_gemm1     <<<gblocks, T, 0, stream>>>(x, W1, dis, hs, N, ntiles);

    k_selfloop_s<<<(t16n + T - 1) / T, T, 0, stream>>>(hs, dis, a1, t16n);
    k_prop_atomic<<<(int)((te + T - 1) / T), T, 0, stream>>>(hs, src, dst, dis, a1, E);
    k_bias_relu_s<<<(t16n + T - 1) / T, T, 0, stream>>>(a1, b1, dis, t16n);

    k_selfloop_s<<<(t16n + T - 1) / T, T, 0, stream>>>(a1, dis, a2, t16n);
    k_prop_atomic<<<(int)((te + T - 1) / T), T, 0, stream>>>(a1, src, dst, dis, a2, E);

    k_out       <<<(N + 3) / 4, T, 0, stream>>>(a2, W2, b2, out, N);
  }
}

// Round 6
// 548.573 us; speedup vs baseline: 1.3881x; 1.2127x over previous
//
#include <hip/hip_runtime.h>

#define FIN 512
#define FMID 16
#define FOUT 64

typedef __attribute__((ext_vector_type(8))) short bf8_t;    // 8 x bf16 (4 VGPR)
typedef __attribute__((ext_vector_type(4))) float f32x4_t;  // MFMA acc

__device__ __forceinline__ unsigned short f2bf_rne(float f) {
  unsigned u = __float_as_uint(f);
  return (unsigned short)((u + 0x7FFFu + ((u >> 16) & 1u)) >> 16);
}
__device__ __forceinline__ float bf2f(unsigned short h) {
  return __uint_as_float(((unsigned)h) << 16);
}

// ====================== CSR build: bucketed counting sort ======================
// Replaces the 3.2M-device-atomic count + scatter (memory-side atomics measured
// at ~20 G/s => 160 us for k_count alone). All per-edge atomics now hit LDS;
// device atomics reduced to ~2 x nblkA x nbuck ~ 0.3M one-off reservations.
// Bucket = 256 consecutive nodes (dst>>8); packed edge = (src<<8)|(dst&255).

#define CHUNK 8192  // edges per pass-A block

__global__ __launch_bounds__(256) void k_bhist(const int* __restrict__ dst,
                                               int* __restrict__ gtot, int E, int nbuck) {
  __shared__ int hist[1024];
  const int t = threadIdx.x;
  const int base = blockIdx.x * CHUNK;
  const int nloc = min(CHUNK, E - base);
  for (int i = t; i < nbuck; i += 256) hist[i] = 0;
  __syncthreads();
  const int nv = nloc & ~3;
  for (int i = t * 4; i < nv; i += 1024) {
    int4 d = *(const int4*)(dst + base + i);
    atomicAdd(&hist[d.x >> 8], 1);
    atomicAdd(&hist[d.y >> 8], 1);
    atomicAdd(&hist[d.z >> 8], 1);
    atomicAdd(&hist[d.w >> 8], 1);
  }
  if (t == 0)
    for (int i = nv; i < nloc; ++i) atomicAdd(&hist[dst[base + i] >> 8], 1);
  __syncthreads();
  for (int i = t; i < nbuck; i += 256) {
    int c = hist[i];
    if (c) atomicAdd(&gtot[i], c);
  }
}

// single-block exclusive scan of bucket totals (nbuck <= 1024).
// gbase: in = totals, out = exclusive prefix; gcur = copy; rowstart[n] = E.
__global__ __launch_bounds__(1024) void k_bscan(int* __restrict__ gbase,
                                                int* __restrict__ gcur,
                                                int* __restrict__ rowstart,
                                                int E, int n, int nbuck) {
  __shared__ int sm[1024];
  int t = threadIdx.x;
  int v = (t < nbuck) ? gbase[t] : 0;
  sm[t] = v;
  __syncthreads();
  for (int off = 1; off < 1024; off <<= 1) {
    int a = (t >= off) ? sm[t - off] : 0;
    __syncthreads();
    sm[t] += a;
    __syncthreads();
  }
  int excl = sm[t] - v;
  if (t < nbuck) {
    gbase[t] = excl;
    gcur[t] = excl;
  }
  if (t == 0) {
    gbase[nbuck] = E;
    rowstart[n] = E;
  }
}

// Scatter edges into bucket-ordered packed[]: per-block LDS histogram, one
// device atomic per (block,bucket) to reserve a segment, then LDS cursor
// atomics assign positions. packed = (src<<8) | (dst&255).
__global__ __launch_bounds__(256) void k_bucketA(const int* __restrict__ src,
                                                 const int* __restrict__ dst,
                                                 int* __restrict__ gcur,
                                                 int* __restrict__ packed,
                                                 int E, int nbuck) {
  __shared__ int hist[1024];
  const int t = threadIdx.x;
  const int base = blockIdx.x * CHUNK;
  const int nloc = min(CHUNK, E - base);
  for (int i = t; i < nbuck; i += 256) hist[i] = 0;
  __syncthreads();
  const int nv = nloc & ~3;
  for (int i = t * 4; i < nv; i += 1024) {
    int4 d = *(const int4*)(dst + base + i);
    atomicAdd(&hist[d.x >> 8], 1);
    atomicAdd(&hist[d.y >> 8], 1);
    atomicAdd(&hist[d.z >> 8], 1);
    atomicAdd(&hist[d.w >> 8], 1);
  }
  if (t == 0)
    for (int i = nv; i < nloc; ++i) atomicAdd(&hist[dst[base + i] >> 8], 1);
  __syncthreads();
  for (int i = t; i < nbuck; i += 256) {
    int c = hist[i];
    hist[i] = c ? atomicAdd(&gcur[i], c) : 0;  // hist becomes global cursor
  }
  __syncthreads();
  for (int i = t * 4; i < nv; i += 1024) {
    int4 d = *(const int4*)(dst + base + i);
    int4 s = *(const int4*)(src + base + i);
    int p0 = atomicAdd(&hist[d.x >> 8], 1);
    int p1 = atomicAdd(&hist[d.y >> 8], 1);
    int p2 = atomicAdd(&hist[d.z >> 8], 1);
    int p3 = atomicAdd(&hist[d.w >> 8], 1);
    packed[p0] = (s.x << 8) | (d.x & 255);
    packed[p1] = (s.y << 8) | (d.y & 255);
    packed[p2] = (s.z << 8) | (d.z & 255);
    packed[p3] = (s.w << 8) | (d.w & 255);
  }
  if (t == 0)
    for (int i = nv; i < nloc; ++i) {
      int d = dst[base + i], s = src[base + i];
      int p = atomicAdd(&hist[d >> 8], 1);
      packed[p] = (s << 8) | (d & 255);
    }
}

// One block per bucket: count 256 node-counters in LDS, block-scan, write
// rowstart + dis, then place src into final csr via LDS cursor atomics.
__global__ __launch_bounds__(256) void k_bucketB(const int* __restrict__ packed,
                                                 const int* __restrict__ gbase,
                                                 int* __restrict__ rowstart,
                                                 float* __restrict__ dis,
                                                 int* __restrict__ csr, int n) {
  __shared__ int cnt[256];
  __shared__ int cur[256];
  const int b = blockIdx.x;
  const int t = threadIdx.x;
  const int beg = gbase[b], end = gbase[b + 1];
  cnt[t] = 0;
  __syncthreads();
  for (int i = beg + t; i < end; i += 256) atomicAdd(&cnt[packed[i] & 255], 1);
  __syncthreads();
  int v = cnt[t];
  cur[t] = v;
  __syncthreads();
  for (int off = 1; off < 256; off <<= 1) {
    int a = (t >= off) ? cur[t - off] : 0;
    __syncthreads();
    cur[t] += a;
    __syncthreads();
  }
  int excl = cur[t] - v;  // local exclusive prefix within bucket
  int node = (b << 8) + t;
  if (node < n) {
    rowstart[node] = beg + excl;
    dis[node] = rsqrtf((float)v + 1.0f);  // +1 self-loop
  }
  __syncthreads();
  cur[t] = beg + excl;  // cursor for placement
  __syncthreads();
  for (int i = beg + t; i < end; i += 256) {
    int p = packed[i];
    int pos = atomicAdd(&cur[p & 255], 1);
    csr[pos] = p >> 8;
  }
}

// ============================ dense layers ============================

// hs[node,0:16] = (x[node,0:512] @ W1) * dis[node] via mfma_f32_16x16x32_bf16.
// One wave per 16-node tile; fp32 accuracy via split-bf16: x = hi + lo,
// h = hi*Whi + lo*Whi + hi*Wlo (error ~2^-16 rel; lo*lo dropped).
// Fragment maps (m89-verified family): A[lane&15][(lane>>4)*8+i],
// B[(lane>>4)*8+i][lane&15], D row=(lane>>4)*4+r col=lane&15.
// W1 pre-split hi/lo into B-frag order in LDS (lane-stride 16 B ->
// conflict-free ds_read_b128). x read straight from global in frag order:
// each wave-load touches 32 full 64B lines (1 KB unique) -> streaming-rate.
__global__ __launch_bounds__(256) void k_gemm1(const float* __restrict__ x,
                                               const float* __restrict__ W1,
                                               const float* __restrict__ dis,
                                               float* __restrict__ hs, int n,
                                               int ntiles) {
  __shared__ short wb_hi[16][64][8];  // 16 KB: B-frag hi, [kstep][lane][i]
  __shared__ short wb_lo[16][64][8];  // 16 KB: B-frag lo
  for (int e = threadIdx.x; e < FIN * FMID; e += 256) {
    int k = e >> 4, j = e & 15;
    int ks = k >> 5, kk = k & 31;
    int L = ((kk >> 3) << 4) + j, i = kk & 7;
    float f = W1[e];
    unsigned short h = f2bf_rne(f);
    wb_hi[ks][L][i] = (short)h;
    wb_lo[ks][L][i] = (short)f2bf_rne(f - bf2f(h));
  }
  __syncthreads();
  const int lane = threadIdx.x & 63;
  const int wid  = threadIdx.x >> 6;
  const int rloc = lane & 15;  // A-row / D-col
  const int q    = lane >> 4;  // k-subchunk / D-row-quad
  for (int tile = blockIdx.x * 4 + wid; tile < ntiles; tile += gridDim.x * 4) {
    int row = tile * 16 + rloc;
    const float4* xr = (const float4*)(x + (size_t)(row < n ? row : n - 1) * FIN);
    f32x4_t acc = {0.f, 0.f, 0.f, 0.f};
#pragma unroll 4
    for (int ks = 0; ks < 16; ++ks) {
      float4 v0 = xr[ks * 8 + q * 2];
      float4 v1 = xr[ks * 8 + q * 2 + 1];
      float fv[8] = {v0.x, v0.y, v0.z, v0.w, v1.x, v1.y, v1.z, v1.w};
      bf8_t ah, al;
#pragma unroll
      for (int i = 0; i < 8; ++i) {
        unsigned short h = f2bf_rne(fv[i]);
        ah[i] = (short)h;
        al[i] = (short)f2bf_rne(fv[i] - bf2f(h));
      }
      bf8_t bh = *(const bf8_t*)&wb_hi[ks][lane][0];
      bf8_t bl = *(const bf8_t*)&wb_lo[ks][lane][0];
      acc = __builtin_amdgcn_mfma_f32_16x16x32_bf16(ah, bh, acc, 0, 0, 0);
      acc = __builtin_amdgcn_mfma_f32_16x16x32_bf16(al, bh, acc, 0, 0, 0);
      acc = __builtin_amdgcn_mfma_f32_16x16x32_bf16(ah, bl, acc, 0, 0, 0);
    }
    int nb = tile * 16 + q * 4;
#pragma unroll
    for (int r = 0; r < 4; ++r) {
      int node = nb + r;
      if (node < n) hs[(size_t)node * FMID + rloc] = acc[r] * dis[node];
    }
  }
}

// CSR gather propagation, float4 rows. 16 lanes per node, split into 4
// subgroups of 4 lanes; subgroup g handles edge slot g, lane-in-subgroup c
// owns features [4c, 4c+4). Per 16-edge batch: one coalesced index load,
// then 16 float4 row-gathers (4 per lane). End: reduce across subgroups.
// Input hs is pre-scaled by dis[src]:
//   raw[d][j] = dis[d] * (hs[d][j] + sum_{s in N(d)} hs[s][j])
// RELU=true (layer 1): out = relu(raw + bias) * dis[d]   (pre-scaled for layer 2)
// RELU=false (layer 2): out = raw                        (k_out adds b2)
template <bool RELU>
__global__ __launch_bounds__(256) void k_prop_csr(const float* __restrict__ hs,
                                                  const int* __restrict__ rowstart,
                                                  const int* __restrict__ csr,
                                                  const float* __restrict__ dis,
                                                  const float* __restrict__ bias,
                                                  float* __restrict__ outp, int n) {
  int t = blockIdx.x * blockDim.x + threadIdx.x;
  int node = t >> 4;
  if (node >= n) return;
  const int j = t & 15;   // lane within 16-group
  const int g = j >> 2;   // subgroup (edge slot)
  const int c = j & 3;    // float4 column
  int beg = rowstart[node], end = rowstart[node + 1];
  float4 acc = make_float4(0.f, 0.f, 0.f, 0.f);
  if (g == 0) {  // self-loop term (already dis[src]-scaled)
    float4 v = ((const float4*)(hs + (size_t)node * FMID))[c];
    acc.x += v.x; acc.y += v.y; acc.z += v.z; acc.w += v.w;
  }
  int i = beg;
  int stop = beg + ((end - beg) & ~15);
  for (; i < stop; i += 16) {
    int sv = csr[i + j];
#pragma unroll
    for (int k = 0; k < 4; ++k) {
      int sidx = __shfl(sv, k * 4 + g, 16);
      float4 v = ((const float4*)(hs + (size_t)sidx * FMID))[c];
      acc.x += v.x; acc.y += v.y; acc.z += v.z; acc.w += v.w;
    }
  }
  // remainder: one edge per step, round-robin over subgroups
  for (int u = 0; i < end; ++i, ++u) {
    int sidx = csr[i];  // uniform within group -> broadcast
    if (g == (u & 3)) {
      float4 v = ((const float4*)(hs + (size_t)sidx * FMID))[c];
      acc.x += v.x; acc.y += v.y; acc.z += v.z; acc.w += v.w;
    }
  }
  // reduce across subgroups (lanes differing in bits 2..3)
#pragma unroll
  for (int off = 4; off <= 8; off <<= 1) {
    acc.x += __shfl_xor(acc.x, off, 16);
    acc.y += __shfl_xor(acc.y, off, 16);
    acc.z += __shfl_xor(acc.z, off, 16);
    acc.w += __shfl_xor(acc.w, off, 16);
  }
  if (g == 0) {
    float dd = dis[node];
    float4 r;
    r.x = dd * acc.x; r.y = dd * acc.y; r.z = dd * acc.z; r.w = dd * acc.w;
    if (RELU) {
      float4 bb = ((const float4*)bias)[c];
      r.x = fmaxf(r.x + bb.x, 0.f) * dd;
      r.y = fmaxf(r.y + bb.y, 0.f) * dd;
      r.z = fmaxf(r.z + bb.z, 0.f) * dd;
      r.w = fmaxf(r.w + bb.w, 0.f) * dd;
    }
    ((float4*)(outp + (size_t)node * FMID))[c] = r;
  }
}

// out[node, 0:64] = log_softmax(a2[node, 0:16] @ W2 + b2). One wave per node.
__global__ __launch_bounds__(256) void k_out(const float* __restrict__ a2,
                                             const float* __restrict__ W2,
                                             const float* __restrict__ b2,
                                             float* __restrict__ out, int n) {
  __shared__ float w[FMID * FOUT];  // 4 KB
  for (int idx = threadIdx.x; idx < FMID * FOUT; idx += 256) w[idx] = W2[idx];
  __syncthreads();
  const int lane = threadIdx.x & 63;
  const int node = blockIdx.x * 4 + (threadIdx.x >> 6);
  if (node >= n) return;
  const float* ar = a2 + (size_t)node * FMID;
  float o = b2[lane];
#pragma unroll
  for (int k = 0; k < FMID; ++k) o += ar[k] * w[k * FOUT + lane];
  float m = o;
#pragma unroll
  for (int off = 32; off >= 1; off >>= 1) m = fmaxf(m, __shfl_xor(m, off));
  float e = __expf(o - m);
  float s = e;
#pragma unroll
  for (int off = 32; off >= 1; off >>= 1) s += __shfl_xor(s, off);
  out[(size_t)node * FOUT + lane] = o - m - __logf(s);
}

// ==================== fallback (atomic path, small ws) ====================

__global__ void k_deg_init(float* __restrict__ deg, int n) {
  int i = blockIdx.x * blockDim.x + threadIdx.x;
  if (i < n) deg[i] = 1.0f;
}
__global__ void k_deg_edges(const int* __restrict__ dst, float* __restrict__ deg, int E) {
  int e = blockIdx.x * blockDim.x + threadIdx.x;
  if (e < E) atomicAdd(&deg[dst[e]], 1.0f);
}
__global__ void k_deg_finish(float* __restrict__ deg, int n) {
  int i = blockIdx.x * blockDim.x + threadIdx.x;
  if (i < n) deg[i] = rsqrtf(deg[i]);
}
__global__ void k_selfloop_s(const float* __restrict__ hs, const float* __restrict__ dis,
                             float* __restrict__ a, int total16) {
  int t = blockIdx.x * blockDim.x + threadIdx.x;
  if (t < total16) a[t] = hs[t] * dis[t >> 4];
}
__global__ void k_prop_atomic(const float* __restrict__ hs, const int* __restrict__ src,
                              const int* __restrict__ dst, const float* __restrict__ dis,
                              float* __restrict__ outp, int E) {
  int t = blockIdx.x * blockDim.x + threadIdx.x;
  int e = t >> 4;
  if (e >= E) return;
  int jj = t & 15;
  int s = src[e], d = dst[e];
  atomicAdd(&outp[(size_t)d * FMID + jj], hs[(size_t)s * FMID + jj] * dis[d]);
}
__global__ void k_bias_relu_s(float* __restrict__ a, const float* __restrict__ b,
                              const float* __restrict__ dis, int total16) {
  int t = blockIdx.x * blockDim.x + threadIdx.x;
  if (t < total16) {
    float v = a[t] + b[t & 15];
    a[t] = (v > 0.f ? v : 0.f) * dis[t >> 4];
  }
}

// ============================ launcher ============================

extern "C" void kernel_launch(void* const* d_in, const int* in_sizes, int n_in,
                              void* d_out, int out_size, void* d_ws, size_t ws_size,
                              hipStream_t stream) {
  const float* x  = (const float*)d_in[0];
  const int* edge = (const int*)d_in[1];
  const float* W1 = (const float*)d_in[2];
  const float* b1 = (const float*)d_in[3];
  const float* W2 = (const float*)d_in[4];
  const float* b2 = (const float*)d_in[5];
  float* out = (float*)d_out;

  const int N = in_sizes[0] / FIN;   // 100000
  const int E = in_sizes[1] / 2;     // 3200000
  const int* src = edge;
  const int* dst = edge + E;

  const int T = 256;
  const int t16n = N * FMID;
  const int ntiles = (N + 15) / 16;  // 6250
  int gblocks = (ntiles + 3) / 4;
  if (gblocks > 2048) gblocks = 2048;

  const int nbuck = (N + 255) >> 8;        // 391
  const int nblkA = (E + CHUNK - 1) / CHUNK;

  // CSR-path workspace (floats): dis[N] | buf0[16N] | buf1[16N], then ints:
  // rowstart[N+1] | gbase[nbuck+1] | gcur[nbuck] | csr[E].
  // packed[E] aliases buf0..buf1 (needs E <= 32N); dead before k_gemm1.
  size_t need_csr = ((size_t)33 * N + (size_t)(N + 1) + (size_t)(2 * nbuck + 1) +
                     (size_t)E) * 4;
  bool new_ok = (ws_size >= need_csr) && ((size_t)E <= (size_t)32 * N) &&
                (nbuck <= 1024) && ((size_t)N < (1u << 23));

  if (new_ok) {
    float* fbase = (float*)d_ws;
    float* dis  = fbase;
    float* buf0 = fbase + (size_t)N;         // hs, later a2
    float* buf1 = fbase + 17 * (size_t)N;    // a1 (scaled)
    int* packed   = (int*)buf0;              // aliases buf0+buf1 (E ints)
    int* ibase    = (int*)(fbase + 33 * (size_t)N);
    int* rowstart = ibase;                   // N+1
    int* gbase    = ibase + (size_t)N + 1;   // nbuck+1 (totals -> excl prefix)
    int* gcur     = gbase + nbuck + 1;       // nbuck
    int* csr      = gcur + nbuck;            // E

    hipMemsetAsync(gbase, 0, (size_t)(nbuck + 1) * sizeof(int), stream);
    k_bhist  <<<nblkA, T, 0, stream>>>(dst, gbase, E, nbuck);
    k_bscan  <<<1, 1024, 0, stream>>>(gbase, gcur, rowstart, E, N, nbuck);
    k_bucketA<<<nblkA, T, 0, stream>>>(src, dst, gcur, packed, E, nbuck);
    k_bucketB<<<nbuck, T, 0, stream>>>(packed, gbase, rowstart, dis, csr, N);

    k_gemm1  <<<gblocks, T, 0, stream>>>(x, W1, dis, buf0, N, ntiles);

    const int PB = (t16n + T - 1) / T;
    k_prop_csr<true>  <<<PB, T, 0, stream>>>(buf0, rowstart, csr, dis, b1, buf1, N);
    k_prop_csr<false> <<<PB, T, 0, stream>>>(buf1, rowstart, csr, dis, b1, buf0, N);
    k_out    <<<(N + 3) / 4, T, 0, stream>>>(buf0, W2, b2, out, N);
  } else {
    // atomic fallback: dis[N] | hs[16N] | a1[16N] | a2[16N] (~19.6 MB)
    float* f   = (float*)d_ws;
    float* dis = f;
    float* hs  = f + (size_t)N;
    float* a1  = f + 17 * (size_t)N;
    float* a2  = f + 33 * (size_t)N;
    const long te = (long)E * FMID;

    k_deg_init  <<<(N + T - 1) / T, T, 0, stream>>>(dis, N);
    k_deg_edges <<<(E + T - 1) / T, T, 0, stream>>>(dst, dis, E);
    k_deg_finish<<<(N + T - 1) / T, T, 0, stream>>>(dis, N);

    k_gemm1     <<<gblocks, T, 0, stream>>>(x, W1, dis, hs, N, ntiles);

    k_selfloop_s<<<(t16n + T - 1) / T, T, 0, stream>>>(hs, dis, a1, t16n);
    k_prop_atomic<<<(int)((te + T - 1) / T), T, 0, stream>>>(hs, src, dst, dis, a1, E);
    k_bias_relu_s<<<(t16n + T - 1) / T, T, 0, stream>>>(a1, b1, dis, t16n);

    k_selfloop_s<<<(t16n + T - 1) / T, T, 0, stream>>>(a1, dis, a2, t16n);
    k_prop_atomic<<<(int)((te + T - 1) / T), T, 0, stream>>>(a1, src, dst, dis, a2, E);

    k_out       <<<(N + 3) / 4, T, 0, stream>>>(a2, W2, b2, out, N);
  }
}